// Round 5
// baseline (507.978 us; speedup 1.0000x reference)
//
#include <hip/hip_runtime.h>
#include <hip/hip_bf16.h>

static constexpr int KDIM = 96;
static constexpr int BSH = 7;              // 128 nodes per bucket
static constexpr int BNODES = 1 << BSH;
static constexpr int MAXBK = 400;          // >= ceil(50000/128)=391
static constexpr int NSLICE = 6;           // 6 x 16-float feature slices

// ---- bucketed CSR build ----------------------------------------------------

__global__ void kb_hist(const int* __restrict__ dst, int* __restrict__ gbcnt,
                        int E, int NBK) {
  __shared__ int h[MAXBK];
  for (int i = threadIdx.x; i < NBK; i += blockDim.x) h[i] = 0;
  __syncthreads();
  for (int e = blockIdx.x * blockDim.x + threadIdx.x; e < E; e += gridDim.x * blockDim.x)
    atomicAdd(&h[dst[e] >> BSH], 1);
  __syncthreads();
  for (int i = threadIdx.x; i < NBK; i += blockDim.x)
    if (h[i]) atomicAdd(&gbcnt[i], h[i]);
}

__global__ void kb_scanb(const int* __restrict__ gbcnt, int* __restrict__ bstart,
                         int* __restrict__ bcur, int NBK) {
  __shared__ int s[512];
  int t = threadIdx.x;
  int v = (t < NBK) ? gbcnt[t] : 0;
  s[t] = v;
  __syncthreads();
  for (int o = 1; o < 512; o <<= 1) {
    int a = (t >= o) ? s[t - o] : 0;
    __syncthreads();
    s[t] += a;
    __syncthreads();
  }
  if (t < NBK) {
    int excl = s[t] - v;
    bstart[t] = excl;
    bcur[t] = excl;
  }
  if (t == 511) bstart[NBK] = s[511];
}

__global__ __launch_bounds__(256) void kb_scatter(const int* __restrict__ src,
                                                  const int* __restrict__ dst,
                                                  int* __restrict__ bcur,
                                                  int2* __restrict__ tmp,
                                                  int E, int NBK, int chunk) {
  __shared__ int h[MAXBK];
  __shared__ int base[MAXBK];
  int lo = blockIdx.x * chunk;
  int hi = min(lo + chunk, E);
  for (int i = threadIdx.x; i < NBK; i += 256) h[i] = 0;
  __syncthreads();
  for (int e = lo + threadIdx.x; e < hi; e += 256) atomicAdd(&h[dst[e] >> BSH], 1);
  __syncthreads();
  for (int i = threadIdx.x; i < NBK; i += 256) {
    int c = h[i];
    base[i] = c ? atomicAdd(&bcur[i], c) : 0;
    h[i] = 0;
  }
  __syncthreads();
  for (int e = lo + threadIdx.x; e < hi; e += 256) {
    int d = dst[e];
    int b = d >> BSH;
    int p = base[b] + atomicAdd(&h[b], 1);
    tmp[p] = make_int2(src[e], d);
  }
}

__global__ __launch_bounds__(256) void kb_cnt(const int2* __restrict__ tmp,
                                              const int* __restrict__ bstart,
                                              int* __restrict__ cnt,
                                              float* __restrict__ dinv, int N) {
  __shared__ int h[BNODES];
  int b = blockIdx.x;
  for (int i = threadIdx.x; i < BNODES; i += 256) h[i] = 0;
  __syncthreads();
  int lo = bstart[b], hi = bstart[b + 1];
  for (int p = lo + threadIdx.x; p < hi; p += 256)
    atomicAdd(&h[tmp[p].y & (BNODES - 1)], 1);
  __syncthreads();
  int v0 = b << BSH;
  for (int i = threadIdx.x; i < BNODES; i += 256) {
    int v = v0 + i;
    if (v < N) {
      int c = h[i];
      cnt[v] = c;
      dinv[v] = rsqrtf((float)c + 1.0f);  // +1 self-loop
    }
  }
}

// scans over PADDED counts (rows padded to multiple of 4 edges)
__global__ void k_scan1(const int* __restrict__ cnt, int* __restrict__ rowstart,
                        int* __restrict__ bsum, int N) {
  __shared__ int s[256];
  int t = threadIdx.x;
  int i = blockIdx.x * 256 + t;
  s[t] = (i < N) ? ((cnt[i] + 3) & ~3) : 0;
  __syncthreads();
  for (int o = 1; o < 256; o <<= 1) {
    int add = (t >= o) ? s[t - o] : 0;
    __syncthreads();
    s[t] += add;
    __syncthreads();
  }
  if (i < N) rowstart[i + 1] = s[t];
  if (t == 255) bsum[blockIdx.x] = s[255];
}

__global__ void k_scan2(int* __restrict__ bsum, int NB) {
  __shared__ int s[1024];
  int t = threadIdx.x;
  s[t] = (t < NB) ? bsum[t] : 0;
  __syncthreads();
  for (int o = 1; o < 1024; o <<= 1) {
    int add = (t >= o) ? s[t - o] : 0;
    __syncthreads();
    s[t] += add;
    __syncthreads();
  }
  if (t < NB) bsum[t] = s[t];
}

__global__ void k_scan3(int* __restrict__ rowstart, const int* __restrict__ bsum, int N) {
  int i = blockIdx.x * blockDim.x + threadIdx.x;
  if (i == 0) rowstart[0] = 0;
  if (i < N && blockIdx.x > 0) rowstart[i + 1] += bsum[blockIdx.x - 1];
}

// ew stores {src*64 (byte offset of 16-float slice row), dinv[src]}.
__global__ __launch_bounds__(256) void kb_final(const int2* __restrict__ tmp,
                                                const int* __restrict__ bstart,
                                                const int* __restrict__ rowstart,
                                                const float* __restrict__ dinv,
                                                int2* __restrict__ ew, int N) {
  __shared__ int prow[BNODES];
  __shared__ int lcur[BNODES];
  int b = blockIdx.x;
  int v0 = b << BSH;
  for (int i = threadIdx.x; i < BNODES; i += 256) {
    int v = v0 + i;
    prow[i] = (v < N) ? rowstart[v] : 0;
    lcur[i] = 0;
  }
  __syncthreads();
  int lo = bstart[b], hi = bstart[b + 1];
  for (int p = lo + threadIdx.x; p < hi; p += 256) {
    int2 sd = tmp[p];
    int dl = sd.y & (BNODES - 1);
    int pos = prow[dl] + atomicAdd(&lcur[dl], 1);
    ew[pos] = make_int2(sd.x << 6, __float_as_int(dinv[sd.x]));
  }
  __syncthreads();
  for (int i = threadIdx.x; i < BNODES; i += 256) {
    int v = v0 + i;
    if (v < N) {
      int c = lcur[i];
      int p = prow[i] + c;
      int end = prow[i] + ((c + 3) & ~3);
      for (; p < end; ++p) ew[p] = make_int2(0, 0);  // w=0: contributes nothing
    }
  }
}

// ---- dense transform -------------------------------------------------------
// SLICED=true writes slice-major [6][N][16] for the feature-sliced aggregation.

template <int DOUT, bool SLICED>
__global__ __launch_bounds__(256) void k_gemm(const float* __restrict__ x,
                                              const float* __restrict__ Wg,
                                              float* __restrict__ out, int N) {
  __shared__ __align__(16) float Wl[KDIM * DOUT];
  __shared__ __align__(16) float xl[64 * 97];
  int tid = threadIdx.x;
  for (int i = tid; i < KDIM * DOUT; i += 256) Wl[i] = Wg[i];
  int base = blockIdx.x * 64;
  for (int i = tid; i < 64 * KDIM; i += 256) {
    int n = i / KDIM, k = i - n * KDIM;
    int gn = base + n;
    xl[n * 97 + k] = (gn < N) ? x[(size_t)gn * KDIM + k] : 0.f;
  }
  __syncthreads();
  const int tl = tid & 7;
  const int tn = tid >> 3;
  constexpr int M = DOUT / 32;
  float4 accA[M], accB[M];
#pragma unroll
  for (int m = 0; m < M; ++m) {
    accA[m] = float4{0.f, 0.f, 0.f, 0.f};
    accB[m] = float4{0.f, 0.f, 0.f, 0.f};
  }
  const float4* W4 = (const float4*)Wl;
#pragma unroll 4
  for (int k = 0; k < KDIM; ++k) {
    float xa = xl[tn * 97 + k];
    float xb = xl[(tn + 32) * 97 + k];
#pragma unroll
    for (int m = 0; m < M; ++m) {
      float4 ww = W4[k * (DOUT / 4) + tl + 8 * m];
      accA[m].x = fmaf(xa, ww.x, accA[m].x);
      accA[m].y = fmaf(xa, ww.y, accA[m].y);
      accA[m].z = fmaf(xa, ww.z, accA[m].z);
      accA[m].w = fmaf(xa, ww.w, accA[m].w);
      accB[m].x = fmaf(xb, ww.x, accB[m].x);
      accB[m].y = fmaf(xb, ww.y, accB[m].y);
      accB[m].z = fmaf(xb, ww.z, accB[m].z);
      accB[m].w = fmaf(xb, ww.w, accB[m].w);
    }
  }
  int nA = base + tn, nB = base + tn + 32;
#pragma unroll
  for (int m = 0; m < M; ++m) {
    int j0 = 4 * (tl + 8 * m);
    if (SLICED) {
      size_t sbase = (size_t)(j0 >> 4) * N * 16 + (j0 & 15);
      if (nA < N) *(float4*)(out + sbase + (size_t)nA * 16) = accA[m];
      if (nB < N) *(float4*)(out + sbase + (size_t)nB * 16) = accB[m];
    } else {
      if (nA < N) *(float4*)(out + (size_t)nA * DOUT + j0) = accA[m];
      if (nB < N) *(float4*)(out + (size_t)nB * DOUT + j0) = accB[m];
    }
  }
}

// ---- feature-sliced aggregation (persistent blocks) ------------------------
// t: [6][N][16] slice-major. 2048 persistent blocks; slot = blockIdx.x & 7
// pins block to one XCD; slots 0..5 each own one 3.2MB slice (L2-resident).
// nt loads/stores keep streams (ew, out) from evicting the slice.

template <bool RELU>
__global__ __launch_bounds__(256) void k_aggF(const float* __restrict__ t,
                                              const int* __restrict__ rowstart,
                                              const int2* __restrict__ ew,
                                              const float* __restrict__ dinv,
                                              const float* __restrict__ bias,
                                              float* __restrict__ out, int N) {
  const int slot = blockIdx.x & 7;
  if (slot >= NSLICE) return;  // 2 idle XCDs: per-XCD L2 BW binds, not CUs
  const int lane = threadIdx.x & 63;
  const int wv = threadIdx.x >> 6;
  const int g = lane >> 4;     // edge group 0..3
  const int f = lane & 15;     // feature within slice
  const int fb = f << 2;
  const char* tb = (const char*)(t + (size_t)slot * N * 16);
  const float bs = bias[slot * 16 + f];
  const int nitem = (N + 3) >> 2;
  const int stride = gridDim.x >> 3;
  for (int item = blockIdx.x >> 3; item < nitem; item += stride) {
    int v = item * 4 + wv;
    if (v >= N) continue;
    float dv = dinv[v];
    float acc = (g == 0) ? dv * *(const float*)(tb + (size_t)v * 64 + fb) : 0.f;
    int e = rowstart[v];
    const int e1 = rowstart[v + 1];  // padded to x4
    for (; e + 8 <= e1; e += 8) {
      long long la = __builtin_nontemporal_load((const long long*)(ew + e + g));
      long long lb = __builtin_nontemporal_load((const long long*)(ew + e + 4 + g));
      float va = *(const float*)(tb + (unsigned)(int)la + fb);
      float vb = *(const float*)(tb + (unsigned)(int)lb + fb);
      acc = fmaf(__int_as_float((int)(la >> 32)), va, acc);
      acc = fmaf(__int_as_float((int)(lb >> 32)), vb, acc);
    }
    if (e < e1) {
      long long la = __builtin_nontemporal_load((const long long*)(ew + e + g));
      acc = fmaf(__int_as_float((int)(la >> 32)),
                 *(const float*)(tb + (unsigned)(int)la + fb), acc);
    }
    acc += __shfl_xor(acc, 16);
    acc += __shfl_xor(acc, 32);
    if (lane < 16) {
      float r = fmaf(dv, acc, bs);
      if (RELU) r = fmaxf(r, 0.f);
      __builtin_nontemporal_store(r, out + (size_t)v * 96 + slot * 16 + f);
    }
  }
}

// D=32 final aggregation (row-major t), half-wave per node, pad-4 CSR.
// ew.x = src*64 -> byte offset into 32-float rows = (src*64)<<1.
__global__ __launch_bounds__(256) void k_agg32(const float* __restrict__ t,
                                               const int* __restrict__ rowstart,
                                               const int2* __restrict__ ew,
                                               const float* __restrict__ dinv,
                                               const float* __restrict__ bias,
                                               float* __restrict__ out, int N) {
  int half = threadIdx.x >> 5;
  int lane = threadIdx.x & 31;
  int v = blockIdx.x * 8 + half;
  if (v >= N) return;
  const char* tb = (const char*)t;
  const int fb = lane << 2;
  float dv = dinv[v];
  float acc = dv * t[(size_t)v * 32 + lane];
  int e = rowstart[v];
  const int e1 = rowstart[v + 1];
  for (; e + 4 <= e1; e += 4) {
    const int4* m4 = (const int4*)(ew + e);
    int4 q0 = m4[0], q1 = m4[1];
    float a0 = *(const float*)(tb + ((size_t)(unsigned)q0.x << 1) + fb);
    float a1 = *(const float*)(tb + ((size_t)(unsigned)q0.z << 1) + fb);
    float a2 = *(const float*)(tb + ((size_t)(unsigned)q1.x << 1) + fb);
    float a3 = *(const float*)(tb + ((size_t)(unsigned)q1.z << 1) + fb);
    acc = fmaf(__int_as_float(q0.y), a0, acc);
    acc = fmaf(__int_as_float(q0.w), a1, acc);
    acc = fmaf(__int_as_float(q1.y), a2, acc);
    acc = fmaf(__int_as_float(q1.w), a3, acc);
  }
  out[(size_t)v * 32 + lane] = fmaf(dv, acc, bias[lane]);
}

// ---- launch ----------------------------------------------------------------

extern "C" void kernel_launch(void* const* d_in, const int* in_sizes, int n_in,
                              void* d_out, int out_size, void* d_ws, size_t ws_size,
                              hipStream_t stream) {
  const float* x  = (const float*)d_in[0];
  const int*   ei = (const int*)d_in[1];
  const float* W1 = (const float*)d_in[2];
  const float* b1 = (const float*)d_in[3];
  const float* W2 = (const float*)d_in[4];
  const float* b2 = (const float*)d_in[5];
  const float* W3 = (const float*)d_in[6];
  const float* b3 = (const float*)d_in[7];
  float* out = (float*)d_out;

  const int N = in_sizes[0] / KDIM;
  const int E = in_sizes[1] / 2;
  const int* src = ei;
  const int* dst = ei + E;
  const int NBK = (N + BNODES - 1) >> BSH;

  char* w = (char*)d_ws;
  size_t off = 0;
  auto alloc = [&](size_t bytes) {
    char* p = w + off;
    off = (off + bytes + 255) & ~(size_t)255;
    return p;
  };
  int*   gbcnt    = (int*)alloc((size_t)MAXBK * 4);
  int*   bstart   = (int*)alloc((size_t)(MAXBK + 1) * 4);
  int*   bcur     = (int*)alloc((size_t)MAXBK * 4);
  int*   cnt      = (int*)alloc((size_t)N * 4);
  float* dinv     = (float*)alloc((size_t)N * 4);
  int*   rowstart = (int*)alloc((size_t)(N + 1) * 4);
  int*   bsum     = (int*)alloc(4096);
  int2*  tmp      = (int2*)alloc((size_t)E * 8);
  int2*  ew       = (int2*)alloc((size_t)(E + 4 * (size_t)N) * 8);  // pad-4 CSR
  float* tbuf     = (float*)alloc((size_t)N * KDIM * 4);
  float* hbuf     = (float*)alloc((size_t)N * KDIM * 4);

  hipMemsetAsync(gbcnt, 0, (size_t)NBK * 4, stream);

  const int gN = (N + 255) / 256;
  const int NCH = 512;
  const int chunk = (E + NCH - 1) / NCH;

  kb_hist<<<256, 256, 0, stream>>>(dst, gbcnt, E, NBK);
  kb_scanb<<<1, 512, 0, stream>>>(gbcnt, bstart, bcur, NBK);
  kb_scatter<<<NCH, 256, 0, stream>>>(src, dst, bcur, tmp, E, NBK, chunk);
  kb_cnt<<<NBK, 256, 0, stream>>>(tmp, bstart, cnt, dinv, N);
  k_scan1<<<gN, 256, 0, stream>>>(cnt, rowstart, bsum, N);
  k_scan2<<<1, 1024, 0, stream>>>(bsum, gN);
  k_scan3<<<gN, 256, 0, stream>>>(rowstart, bsum, N);
  kb_final<<<NBK, 256, 0, stream>>>(tmp, bstart, rowstart, dinv, ew, N);

  const int gG = (N + 63) / 64;
  const int gA = 2048;  // persistent: 256 blocks/XCD = 32 waves/CU
  k_gemm<96, true><<<gG, 256, 0, stream>>>(x, W1, tbuf, N);
  k_aggF<true><<<gA, 256, 0, stream>>>(tbuf, rowstart, ew, dinv, b1, hbuf, N);
  k_gemm<96, true><<<gG, 256, 0, stream>>>(hbuf, W2, tbuf, N);
  k_aggF<true><<<gA, 256, 0, stream>>>(tbuf, rowstart, ew, dinv, b2, hbuf, N);
  k_gemm<32, false><<<gG, 256, 0, stream>>>(hbuf, W3, tbuf, N);
  k_agg32<<<(N + 7) / 8, 256, 0, stream>>>(tbuf, rowstart, ew, dinv, b3, out, N);
}

// Round 7
// 397.281 us; speedup vs baseline: 1.2786x; 1.2786x over previous
//
#include <hip/hip_runtime.h>
#include <hip/hip_bf16.h>

static constexpr int KDIM = 96;
static constexpr int BSH = 7;              // 128 nodes per bucket
static constexpr int BNODES = 1 << BSH;
static constexpr int MAXBK = 400;          // >= ceil(50000/128)=391

// ---- bucketed CSR build ----------------------------------------------------

__global__ void kb_hist(const int* __restrict__ dst, int* __restrict__ gbcnt,
                        int E, int NBK) {
  __shared__ int h[MAXBK];
  for (int i = threadIdx.x; i < NBK; i += blockDim.x) h[i] = 0;
  __syncthreads();
  for (int e = blockIdx.x * blockDim.x + threadIdx.x; e < E; e += gridDim.x * blockDim.x)
    atomicAdd(&h[dst[e] >> BSH], 1);
  __syncthreads();
  for (int i = threadIdx.x; i < NBK; i += blockDim.x)
    if (h[i]) atomicAdd(&gbcnt[i], h[i]);
}

__global__ void kb_scanb(const int* __restrict__ gbcnt, int* __restrict__ bstart,
                         int* __restrict__ bcur, int NBK) {
  __shared__ int s[512];
  int t = threadIdx.x;
  int v = (t < NBK) ? gbcnt[t] : 0;
  s[t] = v;
  __syncthreads();
  for (int o = 1; o < 512; o <<= 1) {
    int a = (t >= o) ? s[t - o] : 0;
    __syncthreads();
    s[t] += a;
    __syncthreads();
  }
  if (t < NBK) {
    int excl = s[t] - v;
    bstart[t] = excl;
    bcur[t] = excl;
  }
  if (t == 511) bstart[NBK] = s[511];
}

__global__ __launch_bounds__(256) void kb_scatter(const int* __restrict__ src,
                                                  const int* __restrict__ dst,
                                                  int* __restrict__ bcur,
                                                  int2* __restrict__ tmp,
                                                  int E, int NBK, int chunk) {
  __shared__ int h[MAXBK];
  __shared__ int base[MAXBK];
  int lo = blockIdx.x * chunk;
  int hi = min(lo + chunk, E);
  for (int i = threadIdx.x; i < NBK; i += 256) h[i] = 0;
  __syncthreads();
  for (int e = lo + threadIdx.x; e < hi; e += 256) atomicAdd(&h[dst[e] >> BSH], 1);
  __syncthreads();
  for (int i = threadIdx.x; i < NBK; i += 256) {
    int c = h[i];
    base[i] = c ? atomicAdd(&bcur[i], c) : 0;
    h[i] = 0;
  }
  __syncthreads();
  for (int e = lo + threadIdx.x; e < hi; e += 256) {
    int d = dst[e];
    int b = d >> BSH;
    int p = base[b] + atomicAdd(&h[b], 1);
    tmp[p] = make_int2(src[e], d);
  }
}

__global__ __launch_bounds__(256) void kb_cnt(const int2* __restrict__ tmp,
                                              const int* __restrict__ bstart,
                                              int* __restrict__ cnt,
                                              float* __restrict__ dinv, int N) {
  __shared__ int h[BNODES];
  int b = blockIdx.x;
  for (int i = threadIdx.x; i < BNODES; i += 256) h[i] = 0;
  __syncthreads();
  int lo = bstart[b], hi = bstart[b + 1];
  for (int p = lo + threadIdx.x; p < hi; p += 256)
    atomicAdd(&h[tmp[p].y & (BNODES - 1)], 1);
  __syncthreads();
  int v0 = b << BSH;
  for (int i = threadIdx.x; i < BNODES; i += 256) {
    int v = v0 + i;
    if (v < N) {
      int c = h[i];
      cnt[v] = c;
      dinv[v] = rsqrtf((float)c + 1.0f);  // +1 self-loop
    }
  }
}

// scans over PADDED counts: rows padded to multiple of 4, minimum 4
__global__ void k_scan1(const int* __restrict__ cnt, int* __restrict__ rowstart,
                        int* __restrict__ bsum, int N) {
  __shared__ int s[256];
  int t = threadIdx.x;
  int i = blockIdx.x * 256 + t;
  int p = 0;
  if (i < N) {
    p = (cnt[i] + 3) & ~3;
    if (p == 0) p = 4;
  }
  s[t] = p;
  __syncthreads();
  for (int o = 1; o < 256; o <<= 1) {
    int add = (t >= o) ? s[t - o] : 0;
    __syncthreads();
    s[t] += add;
    __syncthreads();
  }
  if (i < N) rowstart[i + 1] = s[t];
  if (t == 255) bsum[blockIdx.x] = s[255];
}

__global__ void k_scan2(int* __restrict__ bsum, int NB) {
  __shared__ int s[1024];
  int t = threadIdx.x;
  s[t] = (t < NB) ? bsum[t] : 0;
  __syncthreads();
  for (int o = 1; o < 1024; o <<= 1) {
    int add = (t >= o) ? s[t - o] : 0;
    __syncthreads();
    s[t] += add;
    __syncthreads();
  }
  if (t < NB) bsum[t] = s[t];
}

__global__ void k_scan3(int* __restrict__ rowstart, const int* __restrict__ bsum, int N) {
  int i = blockIdx.x * blockDim.x + threadIdx.x;
  if (i == 0) rowstart[0] = 0;
  if (i < N && blockIdx.x > 0) rowstart[i + 1] += bsum[blockIdx.x - 1];
}

// ew stores {src*64 (byte offset of a 16-float slice row), dinv[src]}.
__global__ __launch_bounds__(256) void kb_final(const int2* __restrict__ tmp,
                                                const int* __restrict__ bstart,
                                                const int* __restrict__ rowstart,
                                                const float* __restrict__ dinv,
                                                int2* __restrict__ ew, int N) {
  __shared__ int prow[BNODES];
  __shared__ int lcur[BNODES];
  int b = blockIdx.x;
  int v0 = b << BSH;
  for (int i = threadIdx.x; i < BNODES; i += 256) {
    int v = v0 + i;
    prow[i] = (v < N) ? rowstart[v] : 0;
    lcur[i] = 0;
  }
  __syncthreads();
  int lo = bstart[b], hi = bstart[b + 1];
  for (int p = lo + threadIdx.x; p < hi; p += 256) {
    int2 sd = tmp[p];
    int dl = sd.y & (BNODES - 1);
    int pos = prow[dl] + atomicAdd(&lcur[dl], 1);
    ew[pos] = make_int2(sd.x << 6, __float_as_int(dinv[sd.x]));
  }
  __syncthreads();
  for (int i = threadIdx.x; i < BNODES; i += 256) {
    int v = v0 + i;
    if (v < N) {
      int c = lcur[i];
      int alloc = (c + 3) & ~3;
      if (alloc == 0) alloc = 4;
      int p = prow[i] + c;
      int end = prow[i] + alloc;
      for (; p < end; ++p) ew[p] = make_int2(0, 0);  // w=0: contributes nothing
    }
  }
}

// ---- dense transform -------------------------------------------------------
// SLICED=true writes slice-major [D/16][N][16] for the sliced aggregation.

template <int DOUT, bool SLICED>
__global__ __launch_bounds__(256) void k_gemm(const float* __restrict__ x,
                                              const float* __restrict__ Wg,
                                              float* __restrict__ out, int N) {
  __shared__ __align__(16) float Wl[KDIM * DOUT];
  __shared__ __align__(16) float xl[64 * 97];
  int tid = threadIdx.x;
  for (int i = tid; i < KDIM * DOUT; i += 256) Wl[i] = Wg[i];
  int base = blockIdx.x * 64;
  for (int i = tid; i < 64 * KDIM; i += 256) {
    int n = i / KDIM, k = i - n * KDIM;
    int gn = base + n;
    xl[n * 97 + k] = (gn < N) ? x[(size_t)gn * KDIM + k] : 0.f;
  }
  __syncthreads();
  const int tl = tid & 7;
  const int tn = tid >> 3;
  constexpr int M = DOUT / 32;
  float4 accA[M], accB[M];
#pragma unroll
  for (int m = 0; m < M; ++m) {
    accA[m] = float4{0.f, 0.f, 0.f, 0.f};
    accB[m] = float4{0.f, 0.f, 0.f, 0.f};
  }
  const float4* W4 = (const float4*)Wl;
#pragma unroll 4
  for (int k = 0; k < KDIM; ++k) {
    float xa = xl[tn * 97 + k];
    float xb = xl[(tn + 32) * 97 + k];
#pragma unroll
    for (int m = 0; m < M; ++m) {
      float4 ww = W4[k * (DOUT / 4) + tl + 8 * m];
      accA[m].x = fmaf(xa, ww.x, accA[m].x);
      accA[m].y = fmaf(xa, ww.y, accA[m].y);
      accA[m].z = fmaf(xa, ww.z, accA[m].z);
      accA[m].w = fmaf(xa, ww.w, accA[m].w);
      accB[m].x = fmaf(xb, ww.x, accB[m].x);
      accB[m].y = fmaf(xb, ww.y, accB[m].y);
      accB[m].z = fmaf(xb, ww.z, accB[m].z);
      accB[m].w = fmaf(xb, ww.w, accB[m].w);
    }
  }
  int nA = base + tn, nB = base + tn + 32;
#pragma unroll
  for (int m = 0; m < M; ++m) {
    int j0 = 4 * (tl + 8 * m);
    if (SLICED) {
      size_t sbase = (size_t)(j0 >> 4) * N * 16 + (j0 & 15);
      if (nA < N) *(float4*)(out + sbase + (size_t)nA * 16) = accA[m];
      if (nB < N) *(float4*)(out + sbase + (size_t)nB * 16) = accB[m];
    } else {
      if (nA < N) *(float4*)(out + (size_t)nA * DOUT + j0) = accA[m];
      if (nB < N) *(float4*)(out + (size_t)nB * DOUT + j0) = accB[m];
    }
  }
}

// ---- feature-sliced aggregation, node-per-group ----------------------------
// t: [D/16][N][16] slice-major. 2048 persistent blocks; slot = blockIdx.x & 7
// pins a block to one XCD; a slice's 3.2MB table stays L2-resident per XCD.
// Each 16-lane group owns ONE node and walks its whole row: 8 independent
// gathers in flight per lane, no cross-group reduction. Rows padded to x4
// (min 4) so the loop is branchless. out is row-major [N][D].

template <int D, bool RELU>
__global__ __launch_bounds__(256) void k_aggF(const float* __restrict__ t,
                                              const int* __restrict__ rowstart,
                                              const long long* __restrict__ ew,
                                              const float* __restrict__ dinv,
                                              const float* __restrict__ bias,
                                              float* __restrict__ out, int N) {
  const int slot = blockIdx.x & 7;
  int slice, vb0, vstep;
  if (D == 96) {
    if (slot >= 6) return;          // 2 idle XCDs: per-XCD L2 BW binds, not CUs
    slice = slot;
    vb0 = blockIdx.x >> 3;
    vstep = gridDim.x >> 3;
  } else {                          // D == 32: 4 slots (XCDs) share each slice
    slice = slot >> 2;
    vb0 = (blockIdx.x >> 3) * 4 + (slot & 3);
    vstep = (gridDim.x >> 3) * 4;
  }
  const int sub = threadIdx.x >> 4;  // node index within item (0..15)
  const int fb = (threadIdx.x & 15) << 2;
  const char* tb = (const char*)(t + (size_t)slice * N * 16);
  const float bs = bias[slice * 16 + (threadIdx.x & 15)];
  const int nitem = (N + 15) >> 4;
  for (int item = vb0; item < nitem; item += vstep) {
    int v = item * 16 + sub;
    bool act = v < N;
    int vc = act ? v : 0;
    float dv = dinv[vc];
    float acc = dv * *(const float*)(tb + (size_t)vc * 64 + fb);
    int e = rowstart[vc];
    int e1 = act ? rowstart[vc + 1] : e;
    for (; e + 8 <= e1; e += 8) {   // 8 edges: 8 independent gathers per lane
      long long m0 = __builtin_nontemporal_load(ew + e);
      long long m1 = __builtin_nontemporal_load(ew + e + 1);
      long long m2 = __builtin_nontemporal_load(ew + e + 2);
      long long m3 = __builtin_nontemporal_load(ew + e + 3);
      long long m4 = __builtin_nontemporal_load(ew + e + 4);
      long long m5 = __builtin_nontemporal_load(ew + e + 5);
      long long m6 = __builtin_nontemporal_load(ew + e + 6);
      long long m7 = __builtin_nontemporal_load(ew + e + 7);
      float a0 = *(const float*)(tb + (unsigned)(int)m0 + fb);
      float a1 = *(const float*)(tb + (unsigned)(int)m1 + fb);
      float a2 = *(const float*)(tb + (unsigned)(int)m2 + fb);
      float a3 = *(const float*)(tb + (unsigned)(int)m3 + fb);
      float a4 = *(const float*)(tb + (unsigned)(int)m4 + fb);
      float a5 = *(const float*)(tb + (unsigned)(int)m5 + fb);
      float a6 = *(const float*)(tb + (unsigned)(int)m6 + fb);
      float a7 = *(const float*)(tb + (unsigned)(int)m7 + fb);
      acc = fmaf(__int_as_float((int)(m0 >> 32)), a0, acc);
      acc = fmaf(__int_as_float((int)(m1 >> 32)), a1, acc);
      acc = fmaf(__int_as_float((int)(m2 >> 32)), a2, acc);
      acc = fmaf(__int_as_float((int)(m3 >> 32)), a3, acc);
      acc = fmaf(__int_as_float((int)(m4 >> 32)), a4, acc);
      acc = fmaf(__int_as_float((int)(m5 >> 32)), a5, acc);
      acc = fmaf(__int_as_float((int)(m6 >> 32)), a6, acc);
      acc = fmaf(__int_as_float((int)(m7 >> 32)), a7, acc);
    }
    if (e < e1) {                   // remainder is exactly 4
      long long m0 = __builtin_nontemporal_load(ew + e);
      long long m1 = __builtin_nontemporal_load(ew + e + 1);
      long long m2 = __builtin_nontemporal_load(ew + e + 2);
      long long m3 = __builtin_nontemporal_load(ew + e + 3);
      float a0 = *(const float*)(tb + (unsigned)(int)m0 + fb);
      float a1 = *(const float*)(tb + (unsigned)(int)m1 + fb);
      float a2 = *(const float*)(tb + (unsigned)(int)m2 + fb);
      float a3 = *(const float*)(tb + (unsigned)(int)m3 + fb);
      acc = fmaf(__int_as_float((int)(m0 >> 32)), a0, acc);
      acc = fmaf(__int_as_float((int)(m1 >> 32)), a1, acc);
      acc = fmaf(__int_as_float((int)(m2 >> 32)), a2, acc);
      acc = fmaf(__int_as_float((int)(m3 >> 32)), a3, acc);
    }
    if (act) {
      float r = fmaf(dv, acc, bs);
      if (RELU) r = fmaxf(r, 0.f);
      out[(size_t)v * D + slice * 16 + (threadIdx.x & 15)] = r;
    }
  }
}

// ---- launch ----------------------------------------------------------------

extern "C" void kernel_launch(void* const* d_in, const int* in_sizes, int n_in,
                              void* d_out, int out_size, void* d_ws, size_t ws_size,
                              hipStream_t stream) {
  const float* x  = (const float*)d_in[0];
  const int*   ei = (const int*)d_in[1];
  const float* W1 = (const float*)d_in[2];
  const float* b1 = (const float*)d_in[3];
  const float* W2 = (const float*)d_in[4];
  const float* b2 = (const float*)d_in[5];
  const float* W3 = (const float*)d_in[6];
  const float* b3 = (const float*)d_in[7];
  float* out = (float*)d_out;

  const int N = in_sizes[0] / KDIM;
  const int E = in_sizes[1] / 2;
  const int* src = ei;
  const int* dst = ei + E;
  const int NBK = (N + BNODES - 1) >> BSH;

  char* w = (char*)d_ws;
  size_t off = 0;
  auto alloc = [&](size_t bytes) {
    char* p = w + off;
    off = (off + bytes + 255) & ~(size_t)255;
    return p;
  };
  int*   gbcnt    = (int*)alloc((size_t)MAXBK * 4);
  int*   bstart   = (int*)alloc((size_t)(MAXBK + 1) * 4);
  int*   bcur     = (int*)alloc((size_t)MAXBK * 4);
  int*   cnt      = (int*)alloc((size_t)N * 4);
  float* dinv     = (float*)alloc((size_t)N * 4);
  int*   rowstart = (int*)alloc((size_t)(N + 1) * 4);
  int*   bsum     = (int*)alloc(4096);
  int2*  tmp      = (int2*)alloc((size_t)E * 8);
  int2*  ew       = (int2*)alloc((size_t)(E + 4 * (size_t)N + 4) * 8);  // pad-4 CSR
  float* tbuf     = (float*)alloc((size_t)N * KDIM * 4);
  float* hbuf     = (float*)alloc((size_t)N * KDIM * 4);

  hipMemsetAsync(gbcnt, 0, (size_t)NBK * 4, stream);

  const int gN = (N + 255) / 256;
  const int NCH = 512;
  const int chunk = (E + NCH - 1) / NCH;

  kb_hist<<<256, 256, 0, stream>>>(dst, gbcnt, E, NBK);
  kb_scanb<<<1, 512, 0, stream>>>(gbcnt, bstart, bcur, NBK);
  kb_scatter<<<NCH, 256, 0, stream>>>(src, dst, bcur, tmp, E, NBK, chunk);
  kb_cnt<<<NBK, 256, 0, stream>>>(tmp, bstart, cnt, dinv, N);
  k_scan1<<<gN, 256, 0, stream>>>(cnt, rowstart, bsum, N);
  k_scan2<<<1, 1024, 0, stream>>>(bsum, gN);
  k_scan3<<<gN, 256, 0, stream>>>(rowstart, bsum, N);
  kb_final<<<NBK, 256, 0, stream>>>(tmp, bstart, rowstart, dinv, ew, N);

  const int gG = (N + 63) / 64;
  const int gA = 2048;  // persistent: 256 blocks per XCD slot
  k_gemm<96, true><<<gG, 256, 0, stream>>>(x, W1, tbuf, N);
  k_aggF<96, true><<<gA, 256, 0, stream>>>(tbuf, rowstart, (const long long*)ew, dinv, b1, hbuf, N);
  k_gemm<96, true><<<gG, 256, 0, stream>>>(hbuf, W2, tbuf, N);
  k_aggF<96, true><<<gA, 256, 0, stream>>>(tbuf, rowstart, (const long long*)ew, dinv, b2, hbuf, N);
  k_gemm<32, true><<<gG, 256, 0, stream>>>(hbuf, W3, tbuf, N);
  k_aggF<32, false><<<gA, 256, 0, stream>>>(tbuf, rowstart, (const long long*)ew, dinv, b3, out, N);
}

// Round 8
// 242.107 us; speedup vs baseline: 2.0982x; 1.6409x over previous
//
#include <hip/hip_runtime.h>
#include <hip/hip_bf16.h>
#include <hip/hip_fp16.h>

static constexpr int KDIM = 96;
static constexpr int BSH = 7;              // 128 nodes per bucket
static constexpr int BNODES = 1 << BSH;
static constexpr int MAXBK = 400;          // >= ceil(50000/128)=391

// ---- bucketed CSR build ----------------------------------------------------

__global__ void kb_hist(const int* __restrict__ dst, int* __restrict__ gbcnt,
                        int E, int NBK) {
  __shared__ int h[MAXBK];
  for (int i = threadIdx.x; i < NBK; i += blockDim.x) h[i] = 0;
  __syncthreads();
  for (int e = blockIdx.x * blockDim.x + threadIdx.x; e < E; e += gridDim.x * blockDim.x)
    atomicAdd(&h[dst[e] >> BSH], 1);
  __syncthreads();
  for (int i = threadIdx.x; i < NBK; i += blockDim.x)
    if (h[i]) atomicAdd(&gbcnt[i], h[i]);
}

__global__ void kb_scanb(const int* __restrict__ gbcnt, int* __restrict__ bstart,
                         int* __restrict__ bcur, int NBK) {
  __shared__ int s[512];
  int t = threadIdx.x;
  int v = (t < NBK) ? gbcnt[t] : 0;
  s[t] = v;
  __syncthreads();
  for (int o = 1; o < 512; o <<= 1) {
    int a = (t >= o) ? s[t - o] : 0;
    __syncthreads();
    s[t] += a;
    __syncthreads();
  }
  if (t < NBK) {
    int excl = s[t] - v;
    bstart[t] = excl;
    bcur[t] = excl;
  }
  if (t == 511) bstart[NBK] = s[511];
}

__global__ __launch_bounds__(256) void kb_scatter(const int* __restrict__ src,
                                                  const int* __restrict__ dst,
                                                  int* __restrict__ bcur,
                                                  int2* __restrict__ tmp,
                                                  int E, int NBK, int chunk) {
  __shared__ int h[MAXBK];
  __shared__ int base[MAXBK];
  int lo = blockIdx.x * chunk;
  int hi = min(lo + chunk, E);
  for (int i = threadIdx.x; i < NBK; i += 256) h[i] = 0;
  __syncthreads();
  for (int e = lo + threadIdx.x; e < hi; e += 256) atomicAdd(&h[dst[e] >> BSH], 1);
  __syncthreads();
  for (int i = threadIdx.x; i < NBK; i += 256) {
    int c = h[i];
    base[i] = c ? atomicAdd(&bcur[i], c) : 0;
    h[i] = 0;
  }
  __syncthreads();
  for (int e = lo + threadIdx.x; e < hi; e += 256) {
    int d = dst[e];
    int b = d >> BSH;
    int p = base[b] + atomicAdd(&h[b], 1);
    tmp[p] = make_int2(src[e], d);
  }
}

__global__ __launch_bounds__(256) void kb_cnt(const int2* __restrict__ tmp,
                                              const int* __restrict__ bstart,
                                              int* __restrict__ cnt,
                                              float* __restrict__ dinv, int N) {
  __shared__ int h[BNODES];
  int b = blockIdx.x;
  for (int i = threadIdx.x; i < BNODES; i += 256) h[i] = 0;
  __syncthreads();
  int lo = bstart[b], hi = bstart[b + 1];
  for (int p = lo + threadIdx.x; p < hi; p += 256)
    atomicAdd(&h[tmp[p].y & (BNODES - 1)], 1);
  __syncthreads();
  int v0 = b << BSH;
  for (int i = threadIdx.x; i < BNODES; i += 256) {
    int v = v0 + i;
    if (v < N) {
      int c = h[i];
      cnt[v] = c;
      dinv[v] = rsqrtf((float)c + 1.0f);  // +1 self-loop
    }
  }
}

// scans over PADDED counts: rows padded to multiple of 4
__global__ void k_scan1(const int* __restrict__ cnt, int* __restrict__ rowstart,
                        int* __restrict__ bsum, int N) {
  __shared__ int s[256];
  int t = threadIdx.x;
  int i = blockIdx.x * 256 + t;
  s[t] = (i < N) ? ((cnt[i] + 3) & ~3) : 0;
  __syncthreads();
  for (int o = 1; o < 256; o <<= 1) {
    int add = (t >= o) ? s[t - o] : 0;
    __syncthreads();
    s[t] += add;
    __syncthreads();
  }
  if (i < N) rowstart[i + 1] = s[t];
  if (t == 255) bsum[blockIdx.x] = s[255];
}

__global__ void k_scan2(int* __restrict__ bsum, int NB) {
  __shared__ int s[1024];
  int t = threadIdx.x;
  s[t] = (t < NB) ? bsum[t] : 0;
  __syncthreads();
  for (int o = 1; o < 1024; o <<= 1) {
    int add = (t >= o) ? s[t - o] : 0;
    __syncthreads();
    s[t] += add;
    __syncthreads();
  }
  if (t < NB) bsum[t] = s[t];
}

__global__ void k_scan3(int* __restrict__ rowstart, const int* __restrict__ bsum, int N) {
  int i = blockIdx.x * blockDim.x + threadIdx.x;
  if (i == 0) rowstart[0] = 0;
  if (i < N && blockIdx.x > 0) rowstart[i + 1] += bsum[blockIdx.x - 1];
}

// ew stores {src, dinv[src] bit-cast}; rows padded to x4 with {0, 0.0f}.
__global__ __launch_bounds__(256) void kb_final(const int2* __restrict__ tmp,
                                                const int* __restrict__ bstart,
                                                const int* __restrict__ rowstart,
                                                const float* __restrict__ dinv,
                                                int2* __restrict__ ew, int N) {
  __shared__ int prow[BNODES];
  __shared__ int lcur[BNODES];
  int b = blockIdx.x;
  int v0 = b << BSH;
  for (int i = threadIdx.x; i < BNODES; i += 256) {
    int v = v0 + i;
    prow[i] = (v < N) ? rowstart[v] : 0;
    lcur[i] = 0;
  }
  __syncthreads();
  int lo = bstart[b], hi = bstart[b + 1];
  for (int p = lo + threadIdx.x; p < hi; p += 256) {
    int2 sd = tmp[p];
    int dl = sd.y & (BNODES - 1);
    int pos = prow[dl] + atomicAdd(&lcur[dl], 1);
    ew[pos] = make_int2(sd.x, __float_as_int(dinv[sd.x]));
  }
  __syncthreads();
  for (int i = threadIdx.x; i < BNODES; i += 256) {
    int v = v0 + i;
    if (v < N) {
      int c = lcur[i];
      int p = prow[i] + c;
      int end = prow[i] + ((c + 3) & ~3);
      for (; p < end; ++p) ew[p] = make_int2(0, 0);  // w=0: contributes nothing
    }
  }
}

// ---- dense transform: f32 in, fp16 out (gather table) ----------------------

static __device__ __forceinline__ unsigned pack_h2(float a, float b) {
  __half2 h = __float22half2_rn(make_float2(a, b));
  return *(unsigned*)&h;
}

template <int DOUT>
__global__ __launch_bounds__(256) void k_gemm(const float* __restrict__ x,
                                              const float* __restrict__ Wg,
                                              __half* __restrict__ out, int N) {
  __shared__ __align__(16) float Wl[KDIM * DOUT];
  __shared__ __align__(16) float xl[64 * 97];
  int tid = threadIdx.x;
  for (int i = tid; i < KDIM * DOUT; i += 256) Wl[i] = Wg[i];
  int base = blockIdx.x * 64;
  for (int i = tid; i < 64 * KDIM; i += 256) {
    int n = i / KDIM, k = i - n * KDIM;
    int gn = base + n;
    xl[n * 97 + k] = (gn < N) ? x[(size_t)gn * KDIM + k] : 0.f;
  }
  __syncthreads();
  const int tl = tid & 7;
  const int tn = tid >> 3;
  constexpr int M = DOUT / 32;
  float4 accA[M], accB[M];
#pragma unroll
  for (int m = 0; m < M; ++m) {
    accA[m] = float4{0.f, 0.f, 0.f, 0.f};
    accB[m] = float4{0.f, 0.f, 0.f, 0.f};
  }
  const float4* W4 = (const float4*)Wl;
#pragma unroll 4
  for (int k = 0; k < KDIM; ++k) {
    float xa = xl[tn * 97 + k];
    float xb = xl[(tn + 32) * 97 + k];
#pragma unroll
    for (int m = 0; m < M; ++m) {
      float4 ww = W4[k * (DOUT / 4) + tl + 8 * m];
      accA[m].x = fmaf(xa, ww.x, accA[m].x);
      accA[m].y = fmaf(xa, ww.y, accA[m].y);
      accA[m].z = fmaf(xa, ww.z, accA[m].z);
      accA[m].w = fmaf(xa, ww.w, accA[m].w);
      accB[m].x = fmaf(xb, ww.x, accB[m].x);
      accB[m].y = fmaf(xb, ww.y, accB[m].y);
      accB[m].z = fmaf(xb, ww.z, accB[m].z);
      accB[m].w = fmaf(xb, ww.w, accB[m].w);
    }
  }
  int nA = base + tn, nB = base + tn + 32;
#pragma unroll
  for (int m = 0; m < M; ++m) {
    int j0 = 4 * (tl + 8 * m);
    if (nA < N)
      *(uint2*)(out + (size_t)nA * DOUT + j0) =
          make_uint2(pack_h2(accA[m].x, accA[m].y), pack_h2(accA[m].z, accA[m].w));
    if (nB < N)
      *(uint2*)(out + (size_t)nB * DOUT + j0) =
          make_uint2(pack_h2(accB[m].x, accB[m].y), pack_h2(accB[m].z, accB[m].w));
  }
}

// ---- aggregation, fp16 gather table, f32 accumulate ------------------------
// D=96: wave per node, lanes 0..47 hold __half2 pairs (192B rows = 3 lines).
// Rows padded to x4 -> branchless 4-deep gather loop (4 independent chains).

template <bool RELU>
__global__ __launch_bounds__(256) void k_agg96h(const __half* __restrict__ t,
                                                const int* __restrict__ rowstart,
                                                const int2* __restrict__ ew,
                                                const float* __restrict__ dinv,
                                                const float* __restrict__ bias,
                                                float* __restrict__ out, int N) {
  int wv = threadIdx.x >> 6;
  int lane = threadIdx.x & 63;
  int v = blockIdx.x * 4 + wv;
  if (v >= N) return;
  const int li = (lane < 48) ? lane : 47;  // lanes 48-63 duplicate lane 47
  const char* tb = (const char*)t;
  const int fb = li << 2;                  // byte offset of __half2 within row
  float dv = dinv[v];
  float2 acc;
  {
    __half2 r = *(const __half2*)(tb + (size_t)v * 192 + fb);
    float2 f = __half22float2(r);
    acc.x = dv * f.x;
    acc.y = dv * f.y;
  }
  int e = rowstart[v];
  const int e1 = rowstart[v + 1];          // padded to x4
  for (; e < e1; e += 4) {
    int2 m0 = ew[e + 0], m1 = ew[e + 1], m2 = ew[e + 2], m3 = ew[e + 3];
    __half2 r0 = *(const __half2*)(tb + (size_t)(unsigned)m0.x * 192 + fb);
    __half2 r1 = *(const __half2*)(tb + (size_t)(unsigned)m1.x * 192 + fb);
    __half2 r2 = *(const __half2*)(tb + (size_t)(unsigned)m2.x * 192 + fb);
    __half2 r3 = *(const __half2*)(tb + (size_t)(unsigned)m3.x * 192 + fb);
    float2 a0 = __half22float2(r0), a1 = __half22float2(r1);
    float2 a2 = __half22float2(r2), a3 = __half22float2(r3);
    float w0 = __int_as_float(m0.y), w1 = __int_as_float(m1.y);
    float w2 = __int_as_float(m2.y), w3 = __int_as_float(m3.y);
    acc.x = fmaf(w0, a0.x, acc.x); acc.y = fmaf(w0, a0.y, acc.y);
    acc.x = fmaf(w1, a1.x, acc.x); acc.y = fmaf(w1, a1.y, acc.y);
    acc.x = fmaf(w2, a2.x, acc.x); acc.y = fmaf(w2, a2.y, acc.y);
    acc.x = fmaf(w3, a3.x, acc.x); acc.y = fmaf(w3, a3.y, acc.y);
  }
  if (lane < 48) {
    float rx = fmaf(dv, acc.x, bias[2 * lane]);
    float ry = fmaf(dv, acc.y, bias[2 * lane + 1]);
    if (RELU) { rx = fmaxf(rx, 0.f); ry = fmaxf(ry, 0.f); }
    ((float2*)(out + (size_t)v * 96))[lane] = make_float2(rx, ry);
  }
}

// D=32: half-wave per node, 32 lanes x 1 fp16 feature (64B rows = 1 line).
// Table is 3.2MB -> L2-resident everywhere. f32 output (final layer).
__global__ __launch_bounds__(256) void k_agg32h(const __half* __restrict__ t,
                                                const int* __restrict__ rowstart,
                                                const int2* __restrict__ ew,
                                                const float* __restrict__ dinv,
                                                const float* __restrict__ bias,
                                                float* __restrict__ out, int N) {
  int half = threadIdx.x >> 5;
  int lane = threadIdx.x & 31;
  int v = blockIdx.x * 8 + half;
  if (v >= N) return;
  const char* tb = (const char*)t;
  const int fb = lane << 1;
  float dv = dinv[v];
  float acc = dv * __half2float(*(const __half*)(tb + (size_t)v * 64 + fb));
  int e = rowstart[v];
  const int e1 = rowstart[v + 1];
  for (; e < e1; e += 4) {
    int2 m0 = ew[e + 0], m1 = ew[e + 1], m2 = ew[e + 2], m3 = ew[e + 3];
    float a0 = __half2float(*(const __half*)(tb + (size_t)(unsigned)m0.x * 64 + fb));
    float a1 = __half2float(*(const __half*)(tb + (size_t)(unsigned)m1.x * 64 + fb));
    float a2 = __half2float(*(const __half*)(tb + (size_t)(unsigned)m2.x * 64 + fb));
    float a3 = __half2float(*(const __half*)(tb + (size_t)(unsigned)m3.x * 64 + fb));
    acc = fmaf(__int_as_float(m0.y), a0, acc);
    acc = fmaf(__int_as_float(m1.y), a1, acc);
    acc = fmaf(__int_as_float(m2.y), a2, acc);
    acc = fmaf(__int_as_float(m3.y), a3, acc);
  }
  out[(size_t)v * 32 + lane] = fmaf(dv, acc, bias[lane]);
}

// ---- launch ----------------------------------------------------------------

extern "C" void kernel_launch(void* const* d_in, const int* in_sizes, int n_in,
                              void* d_out, int out_size, void* d_ws, size_t ws_size,
                              hipStream_t stream) {
  const float* x  = (const float*)d_in[0];
  const int*   ei = (const int*)d_in[1];
  const float* W1 = (const float*)d_in[2];
  const float* b1 = (const float*)d_in[3];
  const float* W2 = (const float*)d_in[4];
  const float* b2 = (const float*)d_in[5];
  const float* W3 = (const float*)d_in[6];
  const float* b3 = (const float*)d_in[7];
  float* out = (float*)d_out;

  const int N = in_sizes[0] / KDIM;
  const int E = in_sizes[1] / 2;
  const int* src = ei;
  const int* dst = ei + E;
  const int NBK = (N + BNODES - 1) >> BSH;

  char* w = (char*)d_ws;
  size_t off = 0;
  auto alloc = [&](size_t bytes) {
    char* p = w + off;
    off = (off + bytes + 255) & ~(size_t)255;
    return p;
  };
  int*    gbcnt    = (int*)alloc((size_t)MAXBK * 4);
  int*    bstart   = (int*)alloc((size_t)(MAXBK + 1) * 4);
  int*    bcur     = (int*)alloc((size_t)MAXBK * 4);
  int*    cnt      = (int*)alloc((size_t)N * 4);
  float*  dinv     = (float*)alloc((size_t)N * 4);
  int*    rowstart = (int*)alloc((size_t)(N + 1) * 4);
  int*    bsum     = (int*)alloc(4096);
  int2*   tmp      = (int2*)alloc((size_t)E * 8);
  int2*   ew       = (int2*)alloc((size_t)(E + 4 * (size_t)N + 4) * 8);  // pad-4 CSR
  __half* t16      = (__half*)alloc((size_t)N * KDIM * 2);
  float*  hbuf     = (float*)alloc((size_t)N * KDIM * 4);

  hipMemsetAsync(gbcnt, 0, (size_t)NBK * 4, stream);

  const int gN = (N + 255) / 256;
  const int NCH = 512;
  const int chunk = (E + NCH - 1) / NCH;

  kb_hist<<<256, 256, 0, stream>>>(dst, gbcnt, E, NBK);
  kb_scanb<<<1, 512, 0, stream>>>(gbcnt, bstart, bcur, NBK);
  kb_scatter<<<NCH, 256, 0, stream>>>(src, dst, bcur, tmp, E, NBK, chunk);
  kb_cnt<<<NBK, 256, 0, stream>>>(tmp, bstart, cnt, dinv, N);
  k_scan1<<<gN, 256, 0, stream>>>(cnt, rowstart, bsum, N);
  k_scan2<<<1, 1024, 0, stream>>>(bsum, gN);
  k_scan3<<<gN, 256, 0, stream>>>(rowstart, bsum, N);
  kb_final<<<NBK, 256, 0, stream>>>(tmp, bstart, rowstart, dinv, ew, N);

  const int gG = (N + 63) / 64;
  const int gA4 = (N + 3) / 4;
  const int gA8 = (N + 7) / 8;
  k_gemm<96><<<gG, 256, 0, stream>>>(x, W1, t16, N);
  k_agg96h<true><<<gA4, 256, 0, stream>>>(t16, rowstart, ew, dinv, b1, hbuf, N);
  k_gemm<96><<<gG, 256, 0, stream>>>(hbuf, W2, t16, N);
  k_agg96h<true><<<gA4, 256, 0, stream>>>(t16, rowstart, ew, dinv, b2, hbuf, N);
  k_gemm<32><<<gG, 256, 0, stream>>>(hbuf, W3, t16, N);
  k_agg32h<<<gA8, 256, 0, stream>>>(t16, rowstart, ew, dinv, b3, out, N);
}

// Round 9
// 179.409 us; speedup vs baseline: 2.8314x; 1.3495x over previous
//
#include <hip/hip_runtime.h>
#include <hip/hip_bf16.h>
#include <hip/hip_fp16.h>

static constexpr int KDIM = 96;
static constexpr int BSH = 7;              // 128 nodes per bucket
static constexpr int BNODES = 1 << BSH;
static constexpr int MAXBK = 400;          // >= ceil(50000/128)=391

typedef _Float16 f16x8 __attribute__((ext_vector_type(8)));
typedef float f32x4 __attribute__((ext_vector_type(4)));

// ---- bucketed CSR build ----------------------------------------------------

__global__ void kb_hist(const int* __restrict__ dst, int* __restrict__ gbcnt,
                        int E, int NBK) {
  __shared__ int h[MAXBK];
  for (int i = threadIdx.x; i < NBK; i += blockDim.x) h[i] = 0;
  __syncthreads();
  for (int e = blockIdx.x * blockDim.x + threadIdx.x; e < E; e += gridDim.x * blockDim.x)
    atomicAdd(&h[dst[e] >> BSH], 1);
  __syncthreads();
  for (int i = threadIdx.x; i < NBK; i += blockDim.x)
    if (h[i]) atomicAdd(&gbcnt[i], h[i]);
}

__global__ void kb_scanb(const int* __restrict__ gbcnt, int* __restrict__ bstart,
                         int* __restrict__ bcur, int NBK) {
  __shared__ int s[512];
  int t = threadIdx.x;
  int v = (t < NBK) ? gbcnt[t] : 0;
  s[t] = v;
  __syncthreads();
  for (int o = 1; o < 512; o <<= 1) {
    int a = (t >= o) ? s[t - o] : 0;
    __syncthreads();
    s[t] += a;
    __syncthreads();
  }
  if (t < NBK) {
    int excl = s[t] - v;
    bstart[t] = excl;
    bcur[t] = excl;
  }
  if (t == 511) bstart[NBK] = s[511];
}

__global__ __launch_bounds__(256) void kb_scatter(const int* __restrict__ src,
                                                  const int* __restrict__ dst,
                                                  int* __restrict__ bcur,
                                                  int2* __restrict__ tmp,
                                                  int E, int NBK, int chunk) {
  __shared__ int h[MAXBK];
  __shared__ int base[MAXBK];
  int lo = blockIdx.x * chunk;
  int hi = min(lo + chunk, E);
  for (int i = threadIdx.x; i < NBK; i += 256) h[i] = 0;
  __syncthreads();
  for (int e = lo + threadIdx.x; e < hi; e += 256) atomicAdd(&h[dst[e] >> BSH], 1);
  __syncthreads();
  for (int i = threadIdx.x; i < NBK; i += 256) {
    int c = h[i];
    base[i] = c ? atomicAdd(&bcur[i], c) : 0;
    h[i] = 0;
  }
  __syncthreads();
  for (int e = lo + threadIdx.x; e < hi; e += 256) {
    int d = dst[e];
    int b = d >> BSH;
    int p = base[b] + atomicAdd(&h[b], 1);
    tmp[p] = make_int2(src[e], d);
  }
}

__global__ __launch_bounds__(256) void kb_cnt(const int2* __restrict__ tmp,
                                              const int* __restrict__ bstart,
                                              int* __restrict__ cnt,
                                              float* __restrict__ dinv, int N) {
  __shared__ int h[BNODES];
  int b = blockIdx.x;
  for (int i = threadIdx.x; i < BNODES; i += 256) h[i] = 0;
  __syncthreads();
  int lo = bstart[b], hi = bstart[b + 1];
  for (int p = lo + threadIdx.x; p < hi; p += 256)
    atomicAdd(&h[tmp[p].y & (BNODES - 1)], 1);
  __syncthreads();
  int v0 = b << BSH;
  for (int i = threadIdx.x; i < BNODES; i += 256) {
    int v = v0 + i;
    if (v < N) {
      int c = h[i];
      cnt[v] = c;
      dinv[v] = rsqrtf((float)c + 1.0f);  // +1 self-loop
    }
  }
}

// scans over PADDED counts: rows padded to multiple of 4
__global__ void k_scan1(const int* __restrict__ cnt, int* __restrict__ rowstart,
                        int* __restrict__ bsum, int N) {
  __shared__ int s[256];
  int t = threadIdx.x;
  int i = blockIdx.x * 256 + t;
  s[t] = (i < N) ? ((cnt[i] + 3) & ~3) : 0;
  __syncthreads();
  for (int o = 1; o < 256; o <<= 1) {
    int add = (t >= o) ? s[t - o] : 0;
    __syncthreads();
    s[t] += add;
    __syncthreads();
  }
  if (i < N) rowstart[i + 1] = s[t];
  if (t == 255) bsum[blockIdx.x] = s[255];
}

__global__ void k_scan2(int* __restrict__ bsum, int NB) {
  __shared__ int s[1024];
  int t = threadIdx.x;
  s[t] = (t < NB) ? bsum[t] : 0;
  __syncthreads();
  for (int o = 1; o < 1024; o <<= 1) {
    int add = (t >= o) ? s[t - o] : 0;
    __syncthreads();
    s[t] += add;
    __syncthreads();
  }
  if (t < NB) bsum[t] = s[t];
}

__global__ void k_scan3(int* __restrict__ rowstart, const int* __restrict__ bsum, int N) {
  int i = blockIdx.x * blockDim.x + threadIdx.x;
  if (i == 0) rowstart[0] = 0;
  if (i < N && blockIdx.x > 0) rowstart[i + 1] += bsum[blockIdx.x - 1];
}

// ew stores {src, dinv[src] bit-cast}; rows padded to x4 with {0, 0.0f}.
__global__ __launch_bounds__(256) void kb_final(const int2* __restrict__ tmp,
                                                const int* __restrict__ bstart,
                                                const int* __restrict__ rowstart,
                                                const float* __restrict__ dinv,
                                                int2* __restrict__ ew, int N) {
  __shared__ int prow[BNODES];
  __shared__ int lcur[BNODES];
  int b = blockIdx.x;
  int v0 = b << BSH;
  for (int i = threadIdx.x; i < BNODES; i += 256) {
    int v = v0 + i;
    prow[i] = (v < N) ? rowstart[v] : 0;
    lcur[i] = 0;
  }
  __syncthreads();
  int lo = bstart[b], hi = bstart[b + 1];
  for (int p = lo + threadIdx.x; p < hi; p += 256) {
    int2 sd = tmp[p];
    int dl = sd.y & (BNODES - 1);
    int pos = prow[dl] + atomicAdd(&lcur[dl], 1);
    ew[pos] = make_int2(sd.x, __float_as_int(dinv[sd.x]));
  }
  __syncthreads();
  for (int i = threadIdx.x; i < BNODES; i += 256) {
    int v = v0 + i;
    if (v < N) {
      int c = lcur[i];
      int p = prow[i] + c;
      int end = prow[i] + ((c + 3) & ~3);
      for (; p < end; ++p) ew[p] = make_int2(0, 0);  // w=0: contributes nothing
    }
  }
}

// ---- MFMA dense transform --------------------------------------------------
// out[n][j] = sum_k A[n][k] * W[k][j], fp16 inputs, f32 accumulate, fp16 out.
// Per block: 4 waves x 16 rows = 64 rows. Only W in LDS, TRANSPOSED Wt[n][k]
// (stride 104 halves: 16B-aligned, 2-way bank alias = free) so each B-fragment
// is one ds_read_b128. A-fragment loaded from global: lane l supplies
// row=(l&15), k=(l>>4)*8+{0..7} (contiguous 16B). C/D: col=l&15,
// row=(l>>4)*4+reg [m89-verified layout].

template <int DOUT, bool AF32>
__global__ __launch_bounds__(256) void k_gemmm(const void* __restrict__ Ap,
                                               const float* __restrict__ Wg,
                                               __half* __restrict__ out, int N) {
  constexpr int WS = 104;
  __shared__ _Float16 Wt[DOUT * WS];
  const int tid = threadIdx.x;
  for (int i = tid; i < 96 * DOUT; i += 256) {
    int k = i / DOUT;
    int j = i - k * DOUT;
    Wt[j * WS + k] = (_Float16)Wg[i];
  }
  __syncthreads();

  const int wave = tid >> 6;
  const int l = tid & 63;
  const int crow = l & 15;
  const int kgrp = l >> 4;

  int r = blockIdx.x * 64 + wave * 16 + crow;
  int rc = (r < N) ? r : (N - 1);

  f16x8 a[3];
  if (AF32) {
    const float* ap = (const float*)Ap + (size_t)rc * 96 + kgrp * 8;
#pragma unroll
    for (int ks = 0; ks < 3; ++ks) {
      float4 u = *(const float4*)(ap + ks * 32);
      float4 w = *(const float4*)(ap + ks * 32 + 4);
      a[ks][0] = (_Float16)u.x; a[ks][1] = (_Float16)u.y;
      a[ks][2] = (_Float16)u.z; a[ks][3] = (_Float16)u.w;
      a[ks][4] = (_Float16)w.x; a[ks][5] = (_Float16)w.y;
      a[ks][6] = (_Float16)w.z; a[ks][7] = (_Float16)w.w;
    }
  } else {
    const _Float16* ap = (const _Float16*)Ap + (size_t)rc * 96 + kgrp * 8;
#pragma unroll
    for (int ks = 0; ks < 3; ++ks) a[ks] = *(const f16x8*)(ap + ks * 32);
  }

  const int rbase = blockIdx.x * 64 + wave * 16 + kgrp * 4;
#pragma unroll
  for (int nt = 0; nt < DOUT / 16; ++nt) {
    f32x4 c = {0.f, 0.f, 0.f, 0.f};
#pragma unroll
    for (int ks = 0; ks < 3; ++ks) {
      f16x8 b = *(const f16x8*)&Wt[(nt * 16 + crow) * WS + ks * 32 + kgrp * 8];
      c = __builtin_amdgcn_mfma_f32_16x16x32_f16(a[ks], b, c, 0, 0, 0);
    }
#pragma unroll
    for (int reg = 0; reg < 4; ++reg) {
      int R = rbase + reg;
      if (R < N) out[(size_t)R * DOUT + nt * 16 + crow] = (__half)c[reg];
    }
  }
}

// ---- aggregation, fp16 gather table, f32 accumulate, fp16 out --------------
// D=96: wave per node, lanes 0..47 hold __half2 pairs (192B rows = 3 lines).

template <bool RELU>
__global__ __launch_bounds__(256) void k_agg96h(const __half* __restrict__ t,
                                                const int* __restrict__ rowstart,
                                                const int2* __restrict__ ew,
                                                const float* __restrict__ dinv,
                                                const float* __restrict__ bias,
                                                __half* __restrict__ out, int N) {
  int wv = threadIdx.x >> 6;
  int lane = threadIdx.x & 63;
  int v = blockIdx.x * 4 + wv;
  if (v >= N) return;
  const int li = (lane < 48) ? lane : 47;  // lanes 48-63 duplicate lane 47
  const char* tb = (const char*)t;
  const int fb = li << 2;                  // byte offset of __half2 within row
  float dv = dinv[v];
  float2 acc;
  {
    __half2 r = *(const __half2*)(tb + (size_t)v * 192 + fb);
    float2 f = __half22float2(r);
    acc.x = dv * f.x;
    acc.y = dv * f.y;
  }
  int e = rowstart[v];
  const int e1 = rowstart[v + 1];          // padded to x4
  for (; e < e1; e += 4) {
    int2 m0 = ew[e + 0], m1 = ew[e + 1], m2 = ew[e + 2], m3 = ew[e + 3];
    __half2 r0 = *(const __half2*)(tb + (size_t)(unsigned)m0.x * 192 + fb);
    __half2 r1 = *(const __half2*)(tb + (size_t)(unsigned)m1.x * 192 + fb);
    __half2 r2 = *(const __half2*)(tb + (size_t)(unsigned)m2.x * 192 + fb);
    __half2 r3 = *(const __half2*)(tb + (size_t)(unsigned)m3.x * 192 + fb);
    float2 a0 = __half22float2(r0), a1 = __half22float2(r1);
    float2 a2 = __half22float2(r2), a3 = __half22float2(r3);
    float w0 = __int_as_float(m0.y), w1 = __int_as_float(m1.y);
    float w2 = __int_as_float(m2.y), w3 = __int_as_float(m3.y);
    acc.x = fmaf(w0, a0.x, acc.x); acc.y = fmaf(w0, a0.y, acc.y);
    acc.x = fmaf(w1, a1.x, acc.x); acc.y = fmaf(w1, a1.y, acc.y);
    acc.x = fmaf(w2, a2.x, acc.x); acc.y = fmaf(w2, a2.y, acc.y);
    acc.x = fmaf(w3, a3.x, acc.x); acc.y = fmaf(w3, a3.y, acc.y);
  }
  if (lane < 48) {
    float rx = fmaf(dv, acc.x, bias[2 * lane]);
    float ry = fmaf(dv, acc.y, bias[2 * lane + 1]);
    if (RELU) { rx = fmaxf(rx, 0.f); ry = fmaxf(ry, 0.f); }
    ((__half2*)(out + (size_t)v * 96))[lane] = __float22half2_rn(make_float2(rx, ry));
  }
}

// D=32: half-wave per node, 32 lanes x 1 fp16 feature (64B rows = 1 line).
// Table is 3.2MB -> L2-resident everywhere. f32 output (final layer).
__global__ __launch_bounds__(256) void k_agg32h(const __half* __restrict__ t,
                                                const int* __restrict__ rowstart,
                                                const int2* __restrict__ ew,
                                                const float* __restrict__ dinv,
                                                const float* __restrict__ bias,
                                                float* __restrict__ out, int N) {
  int half = threadIdx.x >> 5;
  int lane = threadIdx.x & 31;
  int v = blockIdx.x * 8 + half;
  if (v >= N) return;
  const char* tb = (const char*)t;
  const int fb = lane << 1;
  float dv = dinv[v];
  float acc = dv * __half2float(*(const __half*)(tb + (size_t)v * 64 + fb));
  int e = rowstart[v];
  const int e1 = rowstart[v + 1];
  for (; e < e1; e += 4) {
    int2 m0 = ew[e + 0], m1 = ew[e + 1], m2 = ew[e + 2], m3 = ew[e + 3];
    float a0 = __half2float(*(const __half*)(tb + (size_t)(unsigned)m0.x * 64 + fb));
    float a1 = __half2float(*(const __half*)(tb + (size_t)(unsigned)m1.x * 64 + fb));
    float a2 = __half2float(*(const __half*)(tb + (size_t)(unsigned)m2.x * 64 + fb));
    float a3 = __half2float(*(const __half*)(tb + (size_t)(unsigned)m3.x * 64 + fb));
    acc = fmaf(__int_as_float(m0.y), a0, acc);
    acc = fmaf(__int_as_float(m1.y), a1, acc);
    acc = fmaf(__int_as_float(m2.y), a2, acc);
    acc = fmaf(__int_as_float(m3.y), a3, acc);
  }
  out[(size_t)v * 32 + lane] = fmaf(dv, acc, bias[lane]);
}

// ---- launch ----------------------------------------------------------------

extern "C" void kernel_launch(void* const* d_in, const int* in_sizes, int n_in,
                              void* d_out, int out_size, void* d_ws, size_t ws_size,
                              hipStream_t stream) {
  const float* x  = (const float*)d_in[0];
  const int*   ei = (const int*)d_in[1];
  const float* W1 = (const float*)d_in[2];
  const float* b1 = (const float*)d_in[3];
  const float* W2 = (const float*)d_in[4];
  const float* b2 = (const float*)d_in[5];
  const float* W3 = (const float*)d_in[6];
  const float* b3 = (const float*)d_in[7];
  float* out = (float*)d_out;

  const int N = in_sizes[0] / KDIM;
  const int E = in_sizes[1] / 2;
  const int* src = ei;
  const int* dst = ei + E;
  const int NBK = (N + BNODES - 1) >> BSH;

  char* w = (char*)d_ws;
  size_t off = 0;
  auto alloc = [&](size_t bytes) {
    char* p = w + off;
    off = (off + bytes + 255) & ~(size_t)255;
    return p;
  };
  int*    gbcnt    = (int*)alloc((size_t)MAXBK * 4);
  int*    bstart   = (int*)alloc((size_t)(MAXBK + 1) * 4);
  int*    bcur     = (int*)alloc((size_t)MAXBK * 4);
  int*    cnt      = (int*)alloc((size_t)N * 4);
  float*  dinv     = (float*)alloc((size_t)N * 4);
  int*    rowstart = (int*)alloc((size_t)(N + 1) * 4);
  int*    bsum     = (int*)alloc(4096);
  int2*   tmp      = (int2*)alloc((size_t)E * 8);
  int2*   ew       = (int2*)alloc((size_t)(E + 4 * (size_t)N + 4) * 8);  // pad-4 CSR
  __half* tA       = (__half*)alloc((size_t)N * KDIM * 2);
  __half* tB       = (__half*)alloc((size_t)N * KDIM * 2);
  __half* hA       = (__half*)alloc((size_t)N * KDIM * 2);
  __half* hB       = (__half*)alloc((size_t)N * KDIM * 2);
  __half* tC       = (__half*)alloc((size_t)N * 32 * 2);

  hipMemsetAsync(gbcnt, 0, (size_t)NBK * 4, stream);

  const int gN = (N + 255) / 256;
  const int NCH = 512;
  const int chunk = (E + NCH - 1) / NCH;

  kb_hist<<<256, 256, 0, stream>>>(dst, gbcnt, E, NBK);
  kb_scanb<<<1, 512, 0, stream>>>(gbcnt, bstart, bcur, NBK);
  kb_scatter<<<NCH, 256, 0, stream>>>(src, dst, bcur, tmp, E, NBK, chunk);
  kb_cnt<<<NBK, 256, 0, stream>>>(tmp, bstart, cnt, dinv, N);
  k_scan1<<<gN, 256, 0, stream>>>(cnt, rowstart, bsum, N);
  k_scan2<<<1, 1024, 0, stream>>>(bsum, gN);
  k_scan3<<<gN, 256, 0, stream>>>(rowstart, bsum, N);
  kb_final<<<NBK, 256, 0, stream>>>(tmp, bstart, rowstart, dinv, ew, N);

  const int gG = (N + 63) / 64;
  const int gA4 = (N + 3) / 4;
  const int gA8 = (N + 7) / 8;
  k_gemmm<96, true><<<gG, 256, 0, stream>>>(x, W1, tA, N);
  k_agg96h<true><<<gA4, 256, 0, stream>>>(tA, rowstart, ew, dinv, b1, hA, N);
  k_gemmm<96, false><<<gG, 256, 0, stream>>>(hA, W2, tB, N);
  k_agg96h<true><<<gA4, 256, 0, stream>>>(tB, rowstart, ew, dinv, b2, hB, N);
  k_gemmm<32, false><<<gG, 256, 0, stream>>>(hB, W3, tC, N);
  k_agg32h<<<gA8, 256, 0, stream>>>(tC, rowstart, ew, dinv, b3, out, N);
}

// Round 10
// 163.232 us; speedup vs baseline: 3.1120x; 1.0991x over previous
//
#include <hip/hip_runtime.h>
#include <hip/hip_bf16.h>
#include <hip/hip_fp16.h>

static constexpr int KDIM = 96;
static constexpr int BSH = 7;              // 128 nodes per bucket
static constexpr int BNODES = 1 << BSH;
static constexpr int MAXBK = 400;          // >= ceil(50000/128)=391

typedef _Float16 f16x8 __attribute__((ext_vector_type(8)));
typedef float f32x4 __attribute__((ext_vector_type(4)));

// ---- GEMM96 body (f32 A, fp16 out), W transposed in LDS --------------------
__device__ __forceinline__ void gemm96_f32_body(const float* __restrict__ x,
                                                const float* __restrict__ Wg,
                                                __half* __restrict__ out, int N,
                                                int gb, char* sm) {
  _Float16* Wt = (_Float16*)sm;            // [96][104]
  const int tid = threadIdx.x;
  for (int i = tid; i < 96 * 96; i += 256) {
    int k = i / 96, j = i - k * 96;
    Wt[j * 104 + k] = (_Float16)Wg[i];
  }
  __syncthreads();
  const int wave = tid >> 6;
  const int l = tid & 63;
  const int crow = l & 15;
  const int kgrp = l >> 4;
  int r = gb * 64 + wave * 16 + crow;
  int rc = (r < N) ? r : (N - 1);
  f16x8 a[3];
  const float* ap = x + (size_t)rc * 96 + kgrp * 8;
#pragma unroll
  for (int ks = 0; ks < 3; ++ks) {
    float4 u = *(const float4*)(ap + ks * 32);
    float4 w = *(const float4*)(ap + ks * 32 + 4);
    a[ks][0] = (_Float16)u.x; a[ks][1] = (_Float16)u.y;
    a[ks][2] = (_Float16)u.z; a[ks][3] = (_Float16)u.w;
    a[ks][4] = (_Float16)w.x; a[ks][5] = (_Float16)w.y;
    a[ks][6] = (_Float16)w.z; a[ks][7] = (_Float16)w.w;
  }
  const int rbase = gb * 64 + wave * 16 + kgrp * 4;
#pragma unroll
  for (int nt = 0; nt < 6; ++nt) {
    f32x4 c = {0.f, 0.f, 0.f, 0.f};
#pragma unroll
    for (int ks = 0; ks < 3; ++ks) {
      f16x8 b = *(const f16x8*)&Wt[(nt * 16 + crow) * 104 + ks * 32 + kgrp * 8];
      c = __builtin_amdgcn_mfma_f32_16x16x32_f16(a[ks], b, c, 0, 0, 0);
    }
#pragma unroll
    for (int reg = 0; reg < 4; ++reg) {
      int R = rbase + reg;
      if (R < N) out[(size_t)R * 96 + nt * 16 + crow] = (__half)c[reg];
    }
  }
}

// ---- fat kernel: bucket histogram (blocks<256) + GEMM layer1 (rest) --------
__global__ __launch_bounds__(256) void khist_gemm1(const int* __restrict__ dst,
                                                   int* __restrict__ gbcnt,
                                                   int E, int NBK,
                                                   const float* __restrict__ x,
                                                   const float* __restrict__ W1,
                                                   __half* __restrict__ tA, int N) {
  __shared__ __align__(16) char sm[96 * 104 * 2];
  if (blockIdx.x < 256) {
    int* h = (int*)sm;
    for (int i = threadIdx.x; i < NBK; i += 256) h[i] = 0;
    __syncthreads();
    for (int e = blockIdx.x * 256 + threadIdx.x; e < E; e += 256 * 256)
      atomicAdd(&h[dst[e] >> BSH], 1);
    __syncthreads();
    for (int i = threadIdx.x; i < NBK; i += 256)
      if (h[i]) atomicAdd(&gbcnt[i], h[i]);
  } else {
    gemm96_f32_body(x, W1, tA, N, blockIdx.x - 256, sm);
  }
}

__global__ void kb_scanb(const int* __restrict__ gbcnt, int* __restrict__ bstart,
                         int* __restrict__ bcur, int NBK) {
  __shared__ int s[512];
  int t = threadIdx.x;
  int v = (t < NBK) ? gbcnt[t] : 0;
  s[t] = v;
  __syncthreads();
  for (int o = 1; o < 512; o <<= 1) {
    int a = (t >= o) ? s[t - o] : 0;
    __syncthreads();
    s[t] += a;
    __syncthreads();
  }
  if (t < NBK) {
    int excl = s[t] - v;
    bstart[t] = excl;
    bcur[t] = excl;
  }
  if (t == 511) bstart[NBK] = s[511];
}

// scatter packed {src:16 | (dst&127)<<16} into bucket regions
__global__ __launch_bounds__(256) void kb_scatter(const int* __restrict__ src,
                                                  const int* __restrict__ dst,
                                                  int* __restrict__ bcur,
                                                  unsigned* __restrict__ tmp,
                                                  int E, int NBK, int chunk) {
  __shared__ int h[MAXBK];
  __shared__ int base[MAXBK];
  int lo = blockIdx.x * chunk;
  int hi = min(lo + chunk, E);
  for (int i = threadIdx.x; i < NBK; i += 256) h[i] = 0;
  __syncthreads();
  for (int e = lo + threadIdx.x; e < hi; e += 256) atomicAdd(&h[dst[e] >> BSH], 1);
  __syncthreads();
  for (int i = threadIdx.x; i < NBK; i += 256) {
    int c = h[i];
    base[i] = c ? atomicAdd(&bcur[i], c) : 0;
    h[i] = 0;
  }
  __syncthreads();
  for (int e = lo + threadIdx.x; e < hi; e += 256) {
    int d = dst[e];
    int b = d >> BSH;
    int p = base[b] + atomicAdd(&h[b], 1);
    tmp[p] = (unsigned)src[e] | ((unsigned)(d & (BNODES - 1)) << 16);
  }
}

// per-bucket: count, dinv, padded LDS scan, ew-base via global cursor, rs int2
__global__ __launch_bounds__(256) void kb_cnt2(const unsigned* __restrict__ tmp,
                                               const int* __restrict__ bstart,
                                               int* __restrict__ cursor,
                                               float* __restrict__ dinv,
                                               int2* __restrict__ rs, int N) {
  __shared__ int hcnt[BNODES];
  __shared__ int scn[BNODES];
  __shared__ int gbs;
  int b = blockIdx.x;
  int t = threadIdx.x;
  for (int i = t; i < BNODES; i += 256) hcnt[i] = 0;
  __syncthreads();
  int lo = bstart[b], hi = bstart[b + 1];
  for (int p = lo + t; p < hi; p += 256)
    atomicAdd(&hcnt[(tmp[p] >> 16) & (BNODES - 1)], 1);
  __syncthreads();
  int pcnt = 0;
  if (t < BNODES) {
    pcnt = (hcnt[t] + 3) & ~3;
    scn[t] = pcnt;
  }
  __syncthreads();
  for (int o = 1; o < BNODES; o <<= 1) {
    int a = (t < BNODES && t >= o) ? scn[t - o] : 0;
    __syncthreads();
    if (t < BNODES) scn[t] += a;
    __syncthreads();
  }
  if (t == 0) gbs = atomicAdd(cursor, scn[BNODES - 1]);
  __syncthreads();
  if (t < BNODES) {
    int v = (b << BSH) + t;
    if (v < N) {
      int beg = gbs + scn[t] - pcnt;
      rs[v] = make_int2(beg, beg + pcnt);
      dinv[v] = rsqrtf((float)hcnt[t] + 1.0f);  // +1 self-loop
    }
  }
}

// per-bucket final scatter: ew = {src:16 | fp16(dinv[src])<<16}, pad with 0
__global__ __launch_bounds__(256) void kb_final2(const unsigned* __restrict__ tmp,
                                                 const int* __restrict__ bstart,
                                                 const int2* __restrict__ rs,
                                                 const float* __restrict__ dinv,
                                                 unsigned* __restrict__ ew, int N) {
  __shared__ int beg[BNODES];
  __shared__ int endp[BNODES];
  __shared__ int lcur[BNODES];
  int b = blockIdx.x;
  int t = threadIdx.x;
  int v0 = b << BSH;
  if (t < BNODES) {
    int v = v0 + t;
    if (v < N) {
      int2 r = rs[v];
      beg[t] = r.x;
      endp[t] = r.y;
    } else {
      beg[t] = 0;
      endp[t] = 0;
    }
    lcur[t] = 0;
  }
  __syncthreads();
  int lo = bstart[b], hi = bstart[b + 1];
  for (int p = lo + t; p < hi; p += 256) {
    unsigned u = tmp[p];
    int dl = (u >> 16) & (BNODES - 1);
    int s = u & 0xFFFF;
    int pos = beg[dl] + atomicAdd(&lcur[dl], 1);
    unsigned hw = (unsigned)__half_as_ushort(__float2half(dinv[s]));
    ew[pos] = (unsigned)s | (hw << 16);
  }
  __syncthreads();
  if (t < BNODES) {
    int p = beg[t] + lcur[t];
    int end = endp[t];
    for (; p < end; ++p) ew[p] = 0u;  // src=0, w=0: contributes nothing
  }
}

// ---- MFMA dense transform (fp16 A) -----------------------------------------
template <int DOUT>
__global__ __launch_bounds__(256) void k_gemmm(const __half* __restrict__ Ap,
                                               const float* __restrict__ Wg,
                                               __half* __restrict__ out, int N) {
  constexpr int WS = 104;
  __shared__ _Float16 Wt[DOUT * WS];
  const int tid = threadIdx.x;
  for (int i = tid; i < 96 * DOUT; i += 256) {
    int k = i / DOUT;
    int j = i - k * DOUT;
    Wt[j * WS + k] = (_Float16)Wg[i];
  }
  __syncthreads();
  const int wave = tid >> 6;
  const int l = tid & 63;
  const int crow = l & 15;
  const int kgrp = l >> 4;
  int r = blockIdx.x * 64 + wave * 16 + crow;
  int rc = (r < N) ? r : (N - 1);
  f16x8 a[3];
  const _Float16* ap = (const _Float16*)Ap + (size_t)rc * 96 + kgrp * 8;
#pragma unroll
  for (int ks = 0; ks < 3; ++ks) a[ks] = *(const f16x8*)(ap + ks * 32);
  const int rbase = blockIdx.x * 64 + wave * 16 + kgrp * 4;
#pragma unroll
  for (int nt = 0; nt < DOUT / 16; ++nt) {
    f32x4 c = {0.f, 0.f, 0.f, 0.f};
#pragma unroll
    for (int ks = 0; ks < 3; ++ks) {
      f16x8 b = *(const f16x8*)&Wt[(nt * 16 + crow) * WS + ks * 32 + kgrp * 8];
      c = __builtin_amdgcn_mfma_f32_16x16x32_f16(a[ks], b, c, 0, 0, 0);
    }
#pragma unroll
    for (int reg = 0; reg < 4; ++reg) {
      int R = rbase + reg;
      if (R < N) out[(size_t)R * DOUT + nt * 16 + crow] = (__half)c[reg];
    }
  }
}

// ---- aggregation: packed ew {src:16|fp16 w:16}, fp16 table, f32 accum ------
template <bool RELU>
__global__ __launch_bounds__(256) void k_agg96h(const __half* __restrict__ t,
                                                const int2* __restrict__ rs,
                                                const unsigned* __restrict__ ew,
                                                const float* __restrict__ dinv,
                                                const float* __restrict__ bias,
                                                __half* __restrict__ out, int N) {
  int wv = threadIdx.x >> 6;
  int lane = threadIdx.x & 63;
  int v = blockIdx.x * 4 + wv;
  if (v >= N) return;
  const int li = (lane < 48) ? lane : 47;  // lanes 48-63 duplicate lane 47
  const char* tb = (const char*)t;
  const int fb = li << 2;                  // byte offset of __half2 within row
  float dv = dinv[v];
  float2 acc;
  {
    __half2 r = *(const __half2*)(tb + (size_t)v * 192 + fb);
    float2 f = __half22float2(r);
    acc.x = dv * f.x;
    acc.y = dv * f.y;
  }
  int2 range = rs[v];
  int e = range.x;
  const int e1 = range.y;                  // padded to x4, 16B aligned
  for (; e < e1; e += 4) {
    uint4 q = *(const uint4*)(ew + e);     // 4 edges, one dwordx4
    __half2 r0 = *(const __half2*)(tb + (size_t)(q.x & 0xFFFF) * 192 + fb);
    __half2 r1 = *(const __half2*)(tb + (size_t)(q.y & 0xFFFF) * 192 + fb);
    __half2 r2 = *(const __half2*)(tb + (size_t)(q.z & 0xFFFF) * 192 + fb);
    __half2 r3 = *(const __half2*)(tb + (size_t)(q.w & 0xFFFF) * 192 + fb);
    float2 a0 = __half22float2(r0), a1 = __half22float2(r1);
    float2 a2 = __half22float2(r2), a3 = __half22float2(r3);
    float w0 = __half2float(__ushort_as_half((unsigned short)(q.x >> 16)));
    float w1 = __half2float(__ushort_as_half((unsigned short)(q.y >> 16)));
    float w2 = __half2float(__ushort_as_half((unsigned short)(q.z >> 16)));
    float w3 = __half2float(__ushort_as_half((unsigned short)(q.w >> 16)));
    acc.x = fmaf(w0, a0.x, acc.x); acc.y = fmaf(w0, a0.y, acc.y);
    acc.x = fmaf(w1, a1.x, acc.x); acc.y = fmaf(w1, a1.y, acc.y);
    acc.x = fmaf(w2, a2.x, acc.x); acc.y = fmaf(w2, a2.y, acc.y);
    acc.x = fmaf(w3, a3.x, acc.x); acc.y = fmaf(w3, a3.y, acc.y);
  }
  if (lane < 48) {
    float rx = fmaf(dv, acc.x, bias[2 * lane]);
    float ry = fmaf(dv, acc.y, bias[2 * lane + 1]);
    if (RELU) { rx = fmaxf(rx, 0.f); ry = fmaxf(ry, 0.f); }
    ((__half2*)(out + (size_t)v * 96))[lane] = __float22half2_rn(make_float2(rx, ry));
  }
}

// D=32 final layer: half-wave per node, f32 out
__global__ __launch_bounds__(256) void k_agg32h(const __half* __restrict__ t,
                                                const int2* __restrict__ rs,
                                                const unsigned* __restrict__ ew,
                                                const float* __restrict__ dinv,
                                                const float* __restrict__ bias,
                                                float* __restrict__ out, int N) {
  int half = threadIdx.x >> 5;
  int lane = threadIdx.x & 31;
  int v = blockIdx.x * 8 + half;
  if (v >= N) return;
  const char* tb = (const char*)t;
  const int fb = lane << 1;
  float dv = dinv[v];
  float acc = dv * __half2float(*(const __half*)(tb + (size_t)v * 64 + fb));
  int2 range = rs[v];
  int e = range.x;
  const int e1 = range.y;
  for (; e < e1; e += 4) {
    uint4 q = *(const uint4*)(ew + e);
    float a0 = __half2float(*(const __half*)(tb + (size_t)(q.x & 0xFFFF) * 64 + fb));
    float a1 = __half2float(*(const __half*)(tb + (size_t)(q.y & 0xFFFF) * 64 + fb));
    float a2 = __half2float(*(const __half*)(tb + (size_t)(q.z & 0xFFFF) * 64 + fb));
    float a3 = __half2float(*(const __half*)(tb + (size_t)(q.w & 0xFFFF) * 64 + fb));
    acc = fmaf(__half2float(__ushort_as_half((unsigned short)(q.x >> 16))), a0, acc);
    acc = fmaf(__half2float(__ushort_as_half((unsigned short)(q.y >> 16))), a1, acc);
    acc = fmaf(__half2float(__ushort_as_half((unsigned short)(q.z >> 16))), a2, acc);
    acc = fmaf(__half2float(__ushort_as_half((unsigned short)(q.w >> 16))), a3, acc);
  }
  out[(size_t)v * 32 + lane] = fmaf(dv, acc, bias[lane]);
}

// ---- launch ----------------------------------------------------------------

extern "C" void kernel_launch(void* const* d_in, const int* in_sizes, int n_in,
                              void* d_out, int out_size, void* d_ws, size_t ws_size,
                              hipStream_t stream) {
  const float* x  = (const float*)d_in[0];
  const int*   ei = (const int*)d_in[1];
  const float* W1 = (const float*)d_in[2];
  const float* b1 = (const float*)d_in[3];
  const float* W2 = (const float*)d_in[4];
  const float* b2 = (const float*)d_in[5];
  const float* W3 = (const float*)d_in[6];
  const float* b3 = (const float*)d_in[7];
  float* out = (float*)d_out;

  const int N = in_sizes[0] / KDIM;
  const int E = in_sizes[1] / 2;
  const int* src = ei;
  const int* dst = ei + E;
  const int NBK = (N + BNODES - 1) >> BSH;

  char* w = (char*)d_ws;
  size_t off = 0;
  auto alloc = [&](size_t bytes) {
    char* p = w + off;
    off = (off + bytes + 255) & ~(size_t)255;
    return p;
  };
  int*      gbcnt    = (int*)alloc((size_t)(MAXBK + 8) * 4);  // +cursor at [MAXBK]
  int*      bstart   = (int*)alloc((size_t)(MAXBK + 1) * 4);
  int*      bcur     = (int*)alloc((size_t)MAXBK * 4);
  float*    dinv     = (float*)alloc((size_t)N * 4);
  int2*     rs       = (int2*)alloc((size_t)N * 8);
  unsigned* tmp      = (unsigned*)alloc((size_t)E * 4);
  unsigned* ew       = (unsigned*)alloc((size_t)(E + 4 * (size_t)N + 16) * 4);
  __half*   tA       = (__half*)alloc((size_t)N * KDIM * 2);
  __half*   tB       = (__half*)alloc((size_t)N * KDIM * 2);
  __half*   hA       = (__half*)alloc((size_t)N * KDIM * 2);
  __half*   hB       = (__half*)alloc((size_t)N * KDIM * 2);
  __half*   tC       = (__half*)alloc((size_t)N * 32 * 2);
  int*      cursor   = gbcnt + MAXBK;

  hipMemsetAsync(gbcnt, 0, (size_t)(MAXBK + 8) * 4, stream);

  const int NCH = 512;
  const int chunk = (E + NCH - 1) / NCH;
  const int gG = (N + 63) / 64;
  const int gA4 = (N + 3) / 4;
  const int gA8 = (N + 7) / 8;

  khist_gemm1<<<256 + gG, 256, 0, stream>>>(dst, gbcnt, E, NBK, x, W1, tA, N);
  kb_scanb<<<1, 512, 0, stream>>>(gbcnt, bstart, bcur, NBK);
  kb_scatter<<<NCH, 256, 0, stream>>>(src, dst, bcur, tmp, E, NBK, chunk);
  kb_cnt2<<<NBK, 256, 0, stream>>>(tmp, bstart, cursor, dinv, rs, N);
  kb_final2<<<NBK, 256, 0, stream>>>(tmp, bstart, rs, dinv, ew, N);

  k_agg96h<true><<<gA4, 256, 0, stream>>>(tA, rs, ew, dinv, b1, hA, N);
  k_gemmm<96><<<gG, 256, 0, stream>>>(hA, W2, tB, N);
  k_agg96h<true><<<gA4, 256, 0, stream>>>(tB, rs, ew, dinv, b2, hB, N);
  k_gemmm<32><<<gG, 256, 0, stream>>>(hB, W3, tC, N);
  k_agg32h<<<gA8, 256, 0, stream>>>(tC, rs, ew, dinv, b3, out, N);
}